// Round 1
// baseline (222.028 us; speedup 1.0000x reference)
//
#include <hip/hip_runtime.h>
#include <stdint.h>

typedef __attribute__((ext_vector_type(8))) short bf16x8;
typedef __attribute__((ext_vector_type(4))) float f32x4;

#if __has_builtin(__builtin_amdgcn_exp2f)
#define EXP2F(x) __builtin_amdgcn_exp2f(x)
#else
#define EXP2F(x) exp2f(x)
#endif

__device__ __forceinline__ short f2bf(float f) {
    union { float f; uint32_t u; } c; c.f = f;
    return (short)((c.u + 0x7fffu + ((c.u >> 16) & 1u)) >> 16);
}

// async global->LDS 16B/lane: dest = wave-uniform base + lane*16 (m97/m104 semantics)
typedef __attribute__((address_space(1))) void gvoid;
typedef __attribute__((address_space(3))) void lvoid;
__device__ __forceinline__ void async_cp16(const void* g, void* l) {
    __builtin_amdgcn_global_load_lds((gvoid*)g, (lvoid*)l, 16, 0, 0);
}

// ---- prep: Wt2g chunk-major [16 kchunks][192 cols][32 k] bf16 + bcat[192] f32
__global__ void prep_kernel(const float* __restrict__ Wk, const float* __restrict__ bk,
                            const float* __restrict__ Wq, const float* __restrict__ bq,
                            const float* __restrict__ Wv, const float* __restrict__ bv,
                            short* __restrict__ Wt2g, float* __restrict__ bcat) {
    const int col = blockIdx.x;  // 0..191 (0-63=K, 64-127=Q, 128-191=V)
    const float* W; const float* bb; int c0;
    if (col < 64)       { W = Wk; bb = bk; c0 = col; }
    else if (col < 128) { W = Wq; bb = bq; c0 = col - 64; }
    else                { W = Wv; bb = bv; c0 = col - 128; }
    for (int c = threadIdx.x; c < 512; c += blockDim.x)
        Wt2g[(c >> 5) * (192 * 32) + col * 32 + (c & 31)] = f2bf(W[(size_t)c * 64 + c0]);
    if (threadIdx.x == 0) bcat[col] = bb[c0];
}

// ---- fused per-batch kernel, 1024 threads = 16 waves ----
// Phase 1 (QKV projection), 4x4 wave grid: wave (rg=w>>2, cg=w&3) computes
// rows rg*64..+63 x cols cg*48..+47 (4 m-tiles x 3 n-frags, 48 acc VGPRs).
// x is reg-staged (global->VGPR->cvt bf16->ds_write_b128) into per-m-tile
// fragment blocks (1 KB, lane-linear => conflict-free ds_read_b128).
// W staged via global_load_lds as before. Per-kc LDS reads: 112 KB/CU
// (vs 224 KB with the old 16x1 grid) => LDS time ~ MFMA time.
// Phase 2: all-LDS causal attention; q-tile = magic-square perm of wave so
// every SIMD carries equal causal work (sum t+1 = 34 per SIMD).
// LDS layout (dynamic, 118784 B):
//   phase 1: xb0 @0 (16K bf16) | xb1 @16384 | ws0 @32768 (12K) | ws1 @45056
//   phase 2: Ks  @0 (32K) | Qs @32768 | Vts @65536 (32K) | Ps @98304 (20K)
#define PSTR 40

__global__ __launch_bounds__(1024, 4) void fused_kernel(
    const float* __restrict__ x, const short* __restrict__ Wt2g,
    const float* __restrict__ bcat, float* __restrict__ out) {
    extern __shared__ __align__(16) char smem[];

    const int tid = threadIdx.x;
    const int wave = tid >> 6, lane = tid & 63;
    const int quad = lane >> 4, l16 = lane & 15;
    const int b = blockIdx.x;

    // ================= phase 1: QKV projection =================
    const int rg = wave >> 2, cg = wave & 3;

    f32x4 acc[4][3];
#pragma unroll
    for (int m = 0; m < 4; m++)
#pragma unroll
        for (int j = 0; j < 3; j++) acc[m][j] = (f32x4){0.f, 0.f, 0.f, 0.f};

    // x staging: thread (wave, lane) owns element block row=wave*16+l16,
    // k-oct=quad of each chunk (8 consecutive floats = 32 B global read);
    // its lane index IS the consumer A-frag slot => lane-linear ds_write.
    const float* xg = x + ((size_t)b * 256 + wave * 16 + l16) * 512 + quad * 8;

#define STAGE_W(kc, bufp)                                                           \
    if (wave < 12) {                                                                \
        async_cp16(Wt2g + (size_t)(kc) * 6144 + wave * 512 + lane * 8,              \
                   smem + 32768 + (bufp) * 12288 + wave * 1024);                    \
    }

    // prologue: chunk 0
    STAGE_W(0, 0)
    f32x4 xr0 = *(const f32x4*)xg;
    f32x4 xr1 = *(const f32x4*)(xg + 4);
    {
        bf16x8 v;
#pragma unroll
        for (int i = 0; i < 4; i++) { v[i] = f2bf(xr0[i]); v[4 + i] = f2bf(xr1[i]); }
        *(bf16x8*)((short*)smem + wave * 512 + lane * 8) = v;
    }
    __syncthreads();

    for (int kc = 0; kc < 16; kc++) {
        const int buf = kc & 1;
        if (kc < 15) {
            STAGE_W(kc + 1, buf ^ 1)
            xr0 = *(const f32x4*)(xg + (kc + 1) * 32);
            xr1 = *(const f32x4*)(xg + (kc + 1) * 32 + 4);
        }
        const short* wb = (const short*)(smem + 32768 + buf * 12288);
        bf16x8 bfr0 = *(const bf16x8*)&wb[(cg * 48 + l16) * 32 + quad * 8];
        bf16x8 bfr1 = *(const bf16x8*)&wb[(cg * 48 + 16 + l16) * 32 + quad * 8];
        bf16x8 bfr2 = *(const bf16x8*)&wb[(cg * 48 + 32 + l16) * 32 + quad * 8];
        const short* xbr = (const short*)smem + buf * 8192;
#pragma unroll
        for (int m = 0; m < 4; m++) {
            bf16x8 afr = *(const bf16x8*)&xbr[(rg * 4 + m) * 512 + lane * 8];
            acc[m][0] = __builtin_amdgcn_mfma_f32_16x16x32_bf16(afr, bfr0, acc[m][0], 0, 0, 0);
            acc[m][1] = __builtin_amdgcn_mfma_f32_16x16x32_bf16(afr, bfr1, acc[m][1], 0, 0, 0);
            acc[m][2] = __builtin_amdgcn_mfma_f32_16x16x32_bf16(afr, bfr2, acc[m][2], 0, 0, 0);
        }
        if (kc < 15) {
            bf16x8 v;
#pragma unroll
            for (int i = 0; i < 4; i++) { v[i] = f2bf(xr0[i]); v[4 + i] = f2bf(xr1[i]); }
            *(bf16x8*)((short*)smem + (buf ^ 1) * 8192 + wave * 512 + lane * 8) = v;
        }
        __syncthreads();
    }

    // ---- epilogue: C-layout (row=quad*4+r, col=l16) -> swizzled phase-2 LDS ----
    short* Ks  = (short*)smem;
    short* Qs  = (short*)(smem + 32768);
    short* Vts = (short*)(smem + 65536);
    short* Ps  = (short*)(smem + 98304);
#pragma unroll
    for (int j = 0; j < 3; j++) {
        const int col = cg * 48 + j * 16 + l16;
        const float bias = bcat[col];
        const int h = col & 63;
        const int sel = col >> 6;  // wave-uniform per j (base multiple of 16)
#pragma unroll
        for (int m = 0; m < 4; m++) {
#pragma unroll
            for (int r = 0; r < 4; r++) {
                const short v = f2bf(acc[m][j][r] + bias);
                const int row = rg * 64 + m * 16 + quad * 4 + r;
                if (sel == 0)
                    Ks[row * 64 + (((h >> 3) ^ (row & 7)) << 3) + (h & 7)] = v;
                else if (sel == 1)
                    Qs[row * 64 + (((h >> 3) ^ (row & 7)) << 3) + (h & 7)] = v;
                else
                    Vts[h * 256 + (((row >> 3) ^ (h & 7)) << 3) + (row & 7)] = v;
            }
        }
    }
    __syncthreads();

    // ================= phase 2: causal attention, all-LDS =================
    // q-tile = magic-square permutation of wave: SIMD s = w&3 gets tiles
    // {s^0, 4+(s^1), 8+(s^2), 12+(s^3)} -> per-SIMD causal work equalized.
    const int qt = ((wave >> 2) << 2) | ((wave & 3) ^ (wave >> 2));
    const float sc2 = 0.125f * 1.44269504088896340736f;  // 1/sqrt(64) * log2(e)
    short* myP = Ps + wave * (16 * PSTR);

    const int qrow = qt * 16 + l16;
    const int sw = l16 & 7;
    bf16x8 qf0 = *(const bf16x8*)&Qs[qrow * 64 + ((quad ^ sw) << 3)];
    bf16x8 qf1 = *(const bf16x8*)&Qs[qrow * 64 + (((4 + quad) ^ sw) << 3)];

    f32x4 St[16];
#pragma unroll
    for (int i = 0; i < 16; i++) St[i] = (f32x4){0.f, 0.f, 0.f, 0.f};
#pragma unroll
    for (int nt = 0; nt < 16; nt++) if (nt <= qt) {
        const int krow = nt * 16 + l16;
        bf16x8 kf0 = *(const bf16x8*)&Ks[krow * 64 + ((quad ^ sw) << 3)];
        bf16x8 kf1 = *(const bf16x8*)&Ks[krow * 64 + (((4 + quad) ^ sw) << 3)];
        St[nt] = __builtin_amdgcn_mfma_f32_16x16x32_bf16(qf0, kf0, St[nt], 0, 0, 0);
        St[nt] = __builtin_amdgcn_mfma_f32_16x16x32_bf16(qf1, kf1, St[nt], 0, 0, 0);
    }

    // mask + base-2 softmax; C-layout rows = quad*4+r, col = l16
    const int rowq = qt * 16 + quad * 4;
    float mx[4], ls[4];
#pragma unroll
    for (int r = 0; r < 4; r++) mx[r] = -3.0e38f;
#pragma unroll
    for (int nt = 0; nt < 16; nt++) if (nt <= qt) {
        const int cs = nt * 16 + l16;
#pragma unroll
        for (int r = 0; r < 4; r++) {
            float s = (cs <= rowq + r) ? St[nt][r] * sc2 : -3.0e38f;
            St[nt][r] = s;
            mx[r] = fmaxf(mx[r], s);
        }
    }
#pragma unroll
    for (int d = 1; d < 16; d <<= 1)
#pragma unroll
        for (int r = 0; r < 4; r++)
            mx[r] = fmaxf(mx[r], __shfl_xor(mx[r], d, 64));
#pragma unroll
    for (int r = 0; r < 4; r++) ls[r] = 0.f;
#pragma unroll
    for (int nt = 0; nt < 16; nt++) if (nt <= qt) {
#pragma unroll
        for (int r = 0; r < 4; r++) {
            float p = EXP2F(St[nt][r] - mx[r]);
            St[nt][r] = p;                 // St[nt>qt] stays 0 == correct P
            ls[r] += p;
        }
    }
#pragma unroll
    for (int d = 1; d < 16; d <<= 1)
#pragma unroll
        for (int r = 0; r < 4; r++)
            ls[r] += __shfl_xor(ls[r], d, 64);

    // O = P V over 32-s chunks; P via wave-local LDS C->A roundtrip
    f32x4 O[4];
#pragma unroll
    for (int i = 0; i < 4; i++) O[i] = (f32x4){0.f, 0.f, 0.f, 0.f};
    const int nch = (qt + 2) >> 1;         // ceil((qt+1)/2), wave-uniform
#pragma unroll
    for (int c2 = 0; c2 < 8; c2++) if (c2 < nch) {
#pragma unroll
        for (int t2i = 0; t2i < 2; t2i++) {
            const int nt = c2 * 2 + t2i;   // St[nt]=0 beyond diagonal => P=0
#pragma unroll
            for (int r = 0; r < 4; r++)
                myP[(quad * 4 + r) * PSTR + t2i * 16 + l16] = f2bf(St[nt][r]);
        }
        bf16x8 pf = *(const bf16x8*)&myP[l16 * PSTR + quad * 8];
#pragma unroll
        for (int ht = 0; ht < 4; ht++) {
            const int h = ht * 16 + l16;
            bf16x8 vf = *(const bf16x8*)&Vts[h * 256 + (((c2 * 4 + quad) ^ (h & 7)) << 3)];
            O[ht] = __builtin_amdgcn_mfma_f32_16x16x32_bf16(pf, vf, O[ht], 0, 0, 0);
        }
    }

    float rls[4];
#pragma unroll
    for (int r = 0; r < 4; r++) rls[r] = 1.0f / ls[r];
#pragma unroll
    for (int ht = 0; ht < 4; ht++)
#pragma unroll
        for (int r = 0; r < 4; r++)
            out[((size_t)b * 256 + rowq + r) * 64 + ht * 16 + l16] = O[ht][r] * rls[r];
#undef STAGE_W
}

extern "C" void kernel_launch(void* const* d_in, const int* in_sizes, int n_in,
                              void* d_out, int out_size, void* d_ws, size_t ws_size,
                              hipStream_t stream) {
    const float* x  = (const float*)d_in[0];
    const float* Wk = (const float*)d_in[1];
    const float* bk = (const float*)d_in[2];
    const float* Wq = (const float*)d_in[3];
    const float* bq = (const float*)d_in[4];
    const float* Wv = (const float*)d_in[5];
    const float* bv = (const float*)d_in[6];
    float* out = (float*)d_out;

    char* ws = (char*)d_ws;
    short* Wt2g = (short*)(ws);             // 196608 B (chunk-major)
    float* bcat = (float*)(ws + 196608);    // 768 B

    const int smem_bytes = 118784;          // >64KB -> dynamic + attribute
    (void)hipFuncSetAttribute((const void*)fused_kernel,
                              hipFuncAttributeMaxDynamicSharedMemorySize, smem_bytes);

    prep_kernel<<<192, 256, 0, stream>>>(Wk, bk, Wq, bq, Wv, bv, Wt2g, bcat);
    fused_kernel<<<256, 1024, smem_bytes, stream>>>(x, Wt2g, bcat, out);
}